// Round 5
// baseline (3612.397 us; speedup 1.0000x reference)
//
#include <hip/hip_runtime.h>
#include <hip/hip_bf16.h>
#include <stdint.h>

// Problem constants: [T,B,D]=[4096,4,1024], H=4096. f32 inputs, f32 outputs.
// Outputs: soft [B,T] f32 at out[0..16384), hard [B,T] f32 at out[16384..32768).
#define T_STEPS 4096
#define BATCH   4
#define D_IN    1024
#define H_DIM   4096
#define M_ROWS  (T_STEPS * BATCH)

#define MTILE 16      // m-rows per block
#define KC    256     // k-chunk staged in LDS

// ---------------- zero the f32 logits accumulator (ws is poisoned 0xAA) ----------------
__global__ void zero_logits(float* __restrict__ p, int n) {
    int i = blockIdx.x * blockDim.x + threadIdx.x;
    if (i < n) p[i] = 0.f;
}

// --------------- fused MLP: logits[m] += sum_n relu((X.W1)[m][n] + b1[n]) * w2[n] ---------------
// grid (H/1024, M/MTILE, 2), block 256; thread owns 4 consecutive n's; X k-chunk in LDS.
__global__ void __launch_bounds__(256)
naive_fused(const float* __restrict__ X,                                    // [M][D]
            const float* __restrict__ W1b, const float* __restrict__ W1r,   // [D][H]
            const float* __restrict__ b1b, const float* __restrict__ b1r,   // [H]
            const float* __restrict__ w2b, const float* __restrict__ w2r,   // [H]
            float* __restrict__ logits)                                     // [2][B][T]
{
    __shared__ float xs[MTILE * KC];   // 16 KB

    const int t   = threadIdx.x;
    const int mat = blockIdx.z;
    const int n0  = blockIdx.x * 1024;
    const int m0  = blockIdx.y * MTILE;

    const float* W1 = mat ? W1r : W1b;
    const float* b1 = mat ? b1r : b1b;
    const float* w2 = mat ? w2r : w2b;
    float* outl = logits + mat * M_ROWS;

    const int nb = n0 + 4 * t;         // this thread's 4 n's: nb..nb+3

    float hacc[MTILE][4];
#pragma unroll
    for (int m = 0; m < MTILE; ++m)
#pragma unroll
        for (int q = 0; q < 4; ++q) hacc[m][q] = 0.f;

    for (int k0 = 0; k0 < D_IN; k0 += KC) {
        // stage X[m0..m0+16][k0..k0+256] into LDS (coalesced float4)
#pragma unroll
        for (int jj = 0; jj < 4; ++jj) {
            int e  = (t + 256 * jj) * 4;           // flat float index in [0, 4096)
            int mr = e >> 8, col = e & 255;
            *(float4*)(xs + e) = *(const float4*)(X + (size_t)(m0 + mr) * D_IN + k0 + col);
        }
        __syncthreads();

        for (int d4 = 0; d4 < KC; d4 += 4) {
            const float* wp = W1 + (size_t)(k0 + d4) * H_DIM + nb;
            float4 wa = *(const float4*)(wp);
            float4 wb = *(const float4*)(wp + H_DIM);
            float4 wc = *(const float4*)(wp + 2 * H_DIM);
            float4 wd = *(const float4*)(wp + 3 * H_DIM);
#pragma unroll
            for (int m = 0; m < MTILE; ++m) {
                float4 xv = *(const float4*)(xs + m * KC + d4);   // LDS broadcast (uniform addr)
                hacc[m][0] = fmaf(xv.x, wa.x, fmaf(xv.y, wb.x, fmaf(xv.z, wc.x, fmaf(xv.w, wd.x, hacc[m][0]))));
                hacc[m][1] = fmaf(xv.x, wa.y, fmaf(xv.y, wb.y, fmaf(xv.z, wc.y, fmaf(xv.w, wd.y, hacc[m][1]))));
                hacc[m][2] = fmaf(xv.x, wa.z, fmaf(xv.y, wb.z, fmaf(xv.z, wc.z, fmaf(xv.w, wd.z, hacc[m][2]))));
                hacc[m][3] = fmaf(xv.x, wa.w, fmaf(xv.y, wb.w, fmaf(xv.z, wc.w, fmaf(xv.w, wd.w, hacc[m][3]))));
            }
        }
        __syncthreads();   // protect xs before next stage
    }

    // epilogue: relu(h + b1)*w2, reduce this thread's 4 n's, then across the wave, atomic per m
    float4 b1q = *(const float4*)(b1 + nb);
    float4 w2q = *(const float4*)(w2 + nb);
#pragma unroll
    for (int m = 0; m < MTILE; ++m) {
        float s = fmaxf(hacc[m][0] + b1q.x, 0.f) * w2q.x
                + fmaxf(hacc[m][1] + b1q.y, 0.f) * w2q.y
                + fmaxf(hacc[m][2] + b1q.z, 0.f) * w2q.z
                + fmaxf(hacc[m][3] + b1q.w, 0.f) * w2q.w;
        s += __shfl_xor(s, 1, 64);
        s += __shfl_xor(s, 2, 64);
        s += __shfl_xor(s, 4, 64);
        s += __shfl_xor(s, 8, 64);
        s += __shfl_xor(s, 16, 64);
        s += __shfl_xor(s, 32, 64);
        if ((t & 63) == 0) {
            int mg = m0 + m;                        // row m = t*BATCH + b
            atomicAdd(&outl[(mg & (BATCH - 1)) * T_STEPS + (mg >> 2)], s);  // -> [b][t]
        }
    }
}

// ----------------- soft output (f32): out[b*T+t] = logits_b[b][t] + bb2 -----------------
__global__ void soft_out_k(const float* __restrict__ lb,
                           const float* __restrict__ bb2,
                           float* __restrict__ out) {
    int i = blockIdx.x * blockDim.x + threadIdx.x;
    if (i < M_ROWS) out[i] = lb[i] + bb2[0];
}

// ------------------------------- serial LIF scan, 4 lanes (f32 out) -------------------------------
__global__ void lif_scan_k(const float* __restrict__ lb,
                           const float* __restrict__ lrr,
                           const float* __restrict__ bb2p,
                           const float* __restrict__ br2p,
                           float* __restrict__ out) {
    int b = threadIdx.x;
    if (b >= BATCH) return;
    const float bb2 = bb2p[0];
    const float br2 = br2p[0];
    const float* xb = lb  + b * T_STEPS;
    const float* xr = lrr + b * T_STEPS;
    float* hb = out + M_ROWS + b * T_STEPS;
    float v = 0.f;
    for (int t0 = 0; t0 < T_STEPS; t0 += 4) {
        float4 xv = *(const float4*)(xb + t0);
        float4 rv = *(const float4*)(xr + t0);
#pragma unroll
        for (int u = 0; u < 4; ++u) {
            float x  = (u == 0 ? xv.x : u == 1 ? xv.y : u == 2 ? xv.z : xv.w) + bb2;
            float rl = (u == 0 ? rv.x : u == 1 ? rv.y : u == 2 ? rv.z : rv.w) + br2;
            v = v + (x - v) * 0.5f;                  // v += (x - v)/TAU, TAU=2 (exact)
            bool spike = (v >= 1.0f);                // heaviside(v - V_TH)
            hb[t0 + u] = spike ? 1.0f : 0.0f;
            v = (spike || (rl > 0.f)) ? 0.f : v;     // hard reset on spike or forced mask (sigmoid(rl)>0.5 <=> rl>0)
        }
    }
}

extern "C" void kernel_launch(void* const* d_in, const int* in_sizes, int n_in,
                              void* d_out, int out_size, void* d_ws, size_t ws_size,
                              hipStream_t stream) {
    // dict order (confirmed by r3==r4 identity + in_sizes): hidden, Wb1, bb1, Wb2, bb2, Wr1, br1, Wr2, br2
    int ih = 0, iwb1 = 1, ibb1 = 2, iwb2 = 3, ibb2 = 4, iwr1 = 5, ibr1 = 6, iwr2 = 7, ibr2 = 8;
    if (n_in >= 9 && in_sizes[0] != M_ROWS * D_IN && in_sizes[8] == M_ROWS * D_IN) {
        // alphabetical fallback (never observed to fire)
        iwb1 = 0; iwb2 = 1; iwr1 = 2; iwr2 = 3; ibb1 = 4; ibb2 = 5; ibr1 = 6; ibr2 = 7; ih = 8;
    }
    const float* hidden = (const float*)d_in[ih];
    const float* Wb1 = (const float*)d_in[iwb1]; const float* bb1 = (const float*)d_in[ibb1];
    const float* Wb2 = (const float*)d_in[iwb2]; const float* bb2 = (const float*)d_in[ibb2];
    const float* Wr1 = (const float*)d_in[iwr1]; const float* br1 = (const float*)d_in[ibr1];
    const float* Wr2 = (const float*)d_in[iwr2]; const float* br2 = (const float*)d_in[ibr2];
    float* out = (float*)d_out;                    // f32: [soft B*T][hard B*T]

    // ws: f32 logits [2][B][T] at offset 0 (128 KB)
    float* logits = (float*)d_ws;

    zero_logits<<<dim3((2 * M_ROWS + 255) / 256), 256, 0, stream>>>(logits, 2 * M_ROWS);
    naive_fused<<<dim3(H_DIM / 1024, M_ROWS / MTILE, 2), 256, 0, stream>>>(
        hidden, Wb1, Wr1, bb1, br1, Wb2, Wr2, logits);
    soft_out_k<<<dim3(M_ROWS / 256), 256, 0, stream>>>(logits, bb2, out);
    lif_scan_k<<<1, 64, 0, stream>>>(logits, logits + M_ROWS, bb2, br2, out);
}

// Round 6
// 1243.162 us; speedup vs baseline: 2.9058x; 2.9058x over previous
//
#include <hip/hip_runtime.h>
#include <hip/hip_bf16.h>
#include <stdint.h>

// Problem constants: [T,B,D]=[4096,4,1024], H=4096. f32 inputs, f32 outputs.
// Outputs: soft [B,T] f32 at out[0..16384), hard [B,T] f32 at out[16384..32768).
#define T_STEPS 4096
#define BATCH   4
#define D_IN    1024
#define H_DIM   4096
#define M_ROWS  (T_STEPS * BATCH)

typedef __attribute__((ext_vector_type(8))) short bf16x8;
typedef __attribute__((ext_vector_type(4))) float f32x4;

__device__ __forceinline__ float b2f(unsigned short u) {
    union { unsigned int i; float f; } x; x.i = ((unsigned int)u) << 16; return x.f;
}
__device__ __forceinline__ unsigned short f2bf_rne(float f) {
    union { float f; unsigned int u; } v; v.f = f;
    return (unsigned short)((v.u + 0x7FFFu + ((v.u >> 16) & 1u)) >> 16);
}

__device__ __forceinline__ void load_lds16(const unsigned short* g, unsigned short* l) {
    __builtin_amdgcn_global_load_lds(
        (const __attribute__((address_space(1))) void*)g,
        (__attribute__((address_space(3))) void*)l, 16, 0, 0);
}

// ---------------- zero the f32 logits accumulator (ws is poisoned 0xAA) ----------------
__global__ void zero_logits(float* __restrict__ p, int n) {
    int i = blockIdx.x * blockDim.x + threadIdx.x;
    if (i < n) p[i] = 0.f;
}

// ------------- split hidden f32 -> (hi, lo) bf16 arrays, same layout -------------
__global__ void split_x(const float4* __restrict__ X,
                        unsigned short* __restrict__ hi,
                        unsigned short* __restrict__ lo) {
    int i = blockIdx.x * blockDim.x + threadIdx.x;   // over float4 chunks
    float4 x = X[i];
    ushort4 h, l;
    h.x = f2bf_rne(x.x); l.x = f2bf_rne(x.x - b2f(h.x));
    h.y = f2bf_rne(x.y); l.y = f2bf_rne(x.y - b2f(h.y));
    h.z = f2bf_rne(x.z); l.z = f2bf_rne(x.z - b2f(h.z));
    h.w = f2bf_rne(x.w); l.w = f2bf_rne(x.w - b2f(h.w));
    ((ushort4*)hi)[i] = h;
    ((ushort4*)lo)[i] = l;
}

// ------- transpose W f32 [D][H] -> WT (hi,lo) bf16 [H][D], both matrices (z=0/1) -------
__global__ void split_w(const float* __restrict__ w0, const float* __restrict__ w1,
                        unsigned short* __restrict__ hi, unsigned short* __restrict__ lo) {
    __shared__ float tile[64][65];                   // +1 pad: no bank conflicts
    const float* src = blockIdx.z ? w1 : w0;
    const size_t moff = (size_t)blockIdx.z * H_DIM * D_IN;
    const int t  = threadIdx.x;                      // 256 threads
    const int c4 = (t & 15) * 4;
    const int r0 = (t >> 4) * 4;
    const int bx = blockIdx.x * 64;                  // H direction
    const int by = blockIdx.y * 64;                  // D direction
#pragma unroll
    for (int rr = 0; rr < 4; ++rr) {
        int r = r0 + rr;
        float4 v = *(const float4*)(src + (size_t)(by + r) * H_DIM + bx + c4);
        tile[r][c4 + 0] = v.x; tile[r][c4 + 1] = v.y;
        tile[r][c4 + 2] = v.z; tile[r][c4 + 3] = v.w;
    }
    __syncthreads();
#pragma unroll
    for (int rr = 0; rr < 4; ++rr) {
        int c = r0 + rr;                             // H index within tile
        ushort4 h, l;
        float f0 = tile[c4 + 0][c], f1 = tile[c4 + 1][c];
        float f2 = tile[c4 + 2][c], f3 = tile[c4 + 3][c];
        h.x = f2bf_rne(f0); l.x = f2bf_rne(f0 - b2f(h.x));
        h.y = f2bf_rne(f1); l.y = f2bf_rne(f1 - b2f(h.y));
        h.z = f2bf_rne(f2); l.z = f2bf_rne(f2 - b2f(h.z));
        h.w = f2bf_rne(f3); l.w = f2bf_rne(f3 - b2f(h.w));
        size_t o = moff + (size_t)(bx + c) * D_IN + by + c4;
        *(ushort4*)(hi + o) = h;
        *(ushort4*)(lo + o) = l;
    }
}

// ------------- fused split-f32 GEMM + relu + (.)@W2 reduction -------------
// 3 K-phases: Xhi.WThi + Xhi.WTlo + Xlo.WThi ~= f32 X.W (residual ~2^-18 rel)
// logits[m] += sum_n relu(C[m][n] + b1[n]) * w2[n]   (b1, w2 exact f32)
// m97 structure: 128x128 tile, BK=64, 4 waves, 4x4 frags of 16x16x32 bf16 MFMA.
__global__ void __launch_bounds__(256)
gemm_fused3(const unsigned short* __restrict__ Xhi, const unsigned short* __restrict__ Xlo,
            const unsigned short* __restrict__ WThi, const unsigned short* __restrict__ WTlo,
            const float* __restrict__ b1b, const float* __restrict__ b1r,
            const float* __restrict__ w2b, const float* __restrict__ w2r,
            float* __restrict__ logits)              // [2][B][T] f32, atomically accumulated
{
    __shared__ __align__(16) unsigned short Alds[128 * 64];
    __shared__ __align__(16) unsigned short Blds[128 * 64];

    const int t    = threadIdx.x;
    const int wave = t >> 6;
    const int lane = t & 63;
    const int quad = lane >> 4;
    const int lr   = lane & 15;
    const int w_m  = (wave & 1) * 64;
    const int w_n  = (wave >> 1) * 64;

    const int mat = blockIdx.z;
    const int n0  = blockIdx.x * 128;
    const int m0  = blockIdx.y * 128;

    const size_t aoff = (size_t)m0 * D_IN;
    const size_t boff = (size_t)mat * H_DIM * D_IN + (size_t)n0 * D_IN;
    const unsigned short* Aph[3] = { Xhi + aoff, Xhi + aoff, Xlo + aoff };
    const unsigned short* Bph[3] = { WThi + boff, WTlo + boff, WThi + boff };
    const float* b1 = mat ? b1r : b1b;
    const float* w2 = mat ? w2r : w2b;
    float* out = logits + mat * M_ROWS;

    const int srow = t >> 3;        // row within 32-row staging group
    const int scol = (t & 7) * 8;   // bf16 element offset within 64-wide K slice

    f32x4 acc[4][4] = {};

#pragma unroll 1
    for (int ph = 0; ph < 3; ++ph) {
        const unsigned short* A = Aph[ph];
        const unsigned short* B = Bph[ph];
#pragma unroll 1
        for (int kt = 0; kt < D_IN / 64; ++kt) {
            const int k0 = kt * 64;
#pragma unroll
            for (int i = 0; i < 4; ++i) {
                load_lds16(A + (size_t)(i * 32 + srow) * D_IN + k0 + scol, Alds + i * 2048 + wave * 512);
                load_lds16(B + (size_t)(i * 32 + srow) * D_IN + k0 + scol, Blds + i * 2048 + wave * 512);
            }
            __syncthreads();
#pragma unroll
            for (int kc = 0; kc < 2; ++kc) {
                bf16x8 af[4], bfv[4];
#pragma unroll
                for (int i = 0; i < 4; ++i)
                    af[i] = *(const bf16x8*)(Alds + (w_m + i * 16 + lr) * 64 + kc * 32 + quad * 8);
#pragma unroll
                for (int j = 0; j < 4; ++j)
                    bfv[j] = *(const bf16x8*)(Blds + (w_n + j * 16 + lr) * 64 + kc * 32 + quad * 8);
#pragma unroll
                for (int i = 0; i < 4; ++i)
#pragma unroll
                    for (int j = 0; j < 4; ++j)
                        acc[i][j] = __builtin_amdgcn_mfma_f32_16x16x32_bf16(af[i], bfv[j], acc[i][j], 0, 0, 0);
            }
            __syncthreads();
        }
    }

    // epilogue: relu(C + b1)*w2, reduce over this tile's n, accumulate to logits
    float b1v[4], w2v[4];
#pragma unroll
    for (int j = 0; j < 4; ++j) {
        int n = n0 + w_n + j * 16 + lr;              // C/D col = lane&15
        b1v[j] = b1[n];
        w2v[j] = w2[n];
    }
#pragma unroll
    for (int i = 0; i < 4; ++i) {
#pragma unroll
        for (int r = 0; r < 4; ++r) {
            float s = 0.f;
#pragma unroll
            for (int j = 0; j < 4; ++j) {
                float h = acc[i][j][r] + b1v[j];
                s += fmaxf(h, 0.f) * w2v[j];
            }
            s += __shfl_xor(s, 1, 64);
            s += __shfl_xor(s, 2, 64);
            s += __shfl_xor(s, 4, 64);
            s += __shfl_xor(s, 8, 64);
            if (lr == 0) {
                int m = m0 + w_m + i * 16 + quad * 4 + r;   // C/D row = quad*4 + reg
                atomicAdd(&out[(m & (BATCH - 1)) * T_STEPS + (m >> 2)], s);  // -> [b][t]
            }
        }
    }
}

// ----------------- soft output (f32): out[b*T+t] = logits_b[b][t] + bb2 -----------------
__global__ void soft_out_k(const float* __restrict__ lb,
                           const float* __restrict__ bb2,
                           float* __restrict__ out) {
    int i = blockIdx.x * blockDim.x + threadIdx.x;
    if (i < M_ROWS) out[i] = lb[i] + bb2[0];
}

// --------------------------- serial LIF scan, 4 lanes (f32 out) ---------------------------
__global__ void lif_scan_k(const float* __restrict__ lb,
                           const float* __restrict__ lrr,
                           const float* __restrict__ bb2p,
                           const float* __restrict__ br2p,
                           float* __restrict__ out) {
    int b = threadIdx.x;
    if (b >= BATCH) return;
    const float bb2 = bb2p[0];
    const float br2 = br2p[0];
    const float* xb = lb  + b * T_STEPS;
    const float* xr = lrr + b * T_STEPS;
    float* hb = out + M_ROWS + b * T_STEPS;
    float v = 0.f;
    for (int t0 = 0; t0 < T_STEPS; t0 += 4) {
        float4 xv = *(const float4*)(xb + t0);
        float4 rv = *(const float4*)(xr + t0);
#pragma unroll
        for (int u = 0; u < 4; ++u) {
            float x  = (u == 0 ? xv.x : u == 1 ? xv.y : u == 2 ? xv.z : xv.w) + bb2;
            float rl = (u == 0 ? rv.x : u == 1 ? rv.y : u == 2 ? rv.z : rv.w) + br2;
            v = v + (x - v) * 0.5f;                  // v += (x - v)/TAU, TAU=2 (exact)
            bool spike = (v >= 1.0f);                // heaviside(v - V_TH)
            hb[t0 + u] = spike ? 1.0f : 0.0f;
            v = (spike || (rl > 0.f)) ? 0.f : v;     // hard reset on spike or forced mask
        }
    }
}

extern "C" void kernel_launch(void* const* d_in, const int* in_sizes, int n_in,
                              void* d_out, int out_size, void* d_ws, size_t ws_size,
                              hipStream_t stream) {
    // dict order (confirmed): hidden, Wb1, bb1, Wb2, bb2, Wr1, br1, Wr2, br2
    const float* hidden = (const float*)d_in[0];   // [T,B,D] f32
    const float* Wb1    = (const float*)d_in[1];   // [D,H]
    const float* bb1    = (const float*)d_in[2];   // [H]
    const float* Wb2    = (const float*)d_in[3];   // [H,1]
    const float* bb2    = (const float*)d_in[4];   // [1]
    const float* Wr1    = (const float*)d_in[5];
    const float* br1    = (const float*)d_in[6];
    const float* Wr2    = (const float*)d_in[7];
    const float* br2    = (const float*)d_in[8];
    float* out = (float*)d_out;                    // f32: [soft B*T][hard B*T]

    // ws layout (96.13 MB, fits — ran in round 2): Xhi 32MB | Xlo 32MB | WThi 16MB | WTlo 16MB | logits 128KB
    unsigned short* Xhi  = (unsigned short*)d_ws;
    unsigned short* Xlo  = Xhi  + (size_t)M_ROWS * D_IN;
    unsigned short* WThi = Xlo  + (size_t)M_ROWS * D_IN;
    unsigned short* WTlo = WThi + (size_t)2 * H_DIM * D_IN;
    float* logits = (float*)(WTlo + (size_t)2 * H_DIM * D_IN);

    zero_logits<<<dim3((2 * M_ROWS + 255) / 256), 256, 0, stream>>>(logits, 2 * M_ROWS);
    split_x<<<dim3(M_ROWS * D_IN / 4 / 256), 256, 0, stream>>>((const float4*)hidden, Xhi, Xlo);
    split_w<<<dim3(H_DIM / 64, D_IN / 64, 2), 256, 0, stream>>>(Wb1, Wr1, WThi, WTlo);
    gemm_fused3<<<dim3(H_DIM / 128, M_ROWS / 128, 2), 256, 0, stream>>>(
        Xhi, Xlo, WThi, WTlo, bb1, br1, Wb2, Wr2, logits);
    soft_out_k<<<dim3(M_ROWS / 256), 256, 0, stream>>>(logits, bb2, out);
    lif_scan_k<<<1, 64, 0, stream>>>(logits, logits + M_ROWS, bb2, br2, out);
}

// Round 7
// 1072.660 us; speedup vs baseline: 3.3677x; 1.1590x over previous
//
#include <hip/hip_runtime.h>
#include <hip/hip_bf16.h>
#include <stdint.h>

// Problem constants: [T,B,D]=[4096,4,1024], H=4096. f32 inputs, f32 outputs.
// Outputs: soft [B,T] f32 at out[0..16384), hard [B,T] f32 at out[16384..32768).
#define T_STEPS 4096
#define BATCH   4
#define D_IN    1024
#define H_DIM   4096
#define M_ROWS  (T_STEPS * BATCH)

typedef __attribute__((ext_vector_type(8))) short bf16x8;
typedef __attribute__((ext_vector_type(4))) float f32x4;

__device__ __forceinline__ float b2f(unsigned short u) {
    union { unsigned int i; float f; } x; x.i = ((unsigned int)u) << 16; return x.f;
}
__device__ __forceinline__ unsigned short f2bf_rne(float f) {
    union { float f; unsigned int u; } v; v.f = f;
    return (unsigned short)((v.u + 0x7FFFu + ((v.u >> 16) & 1u)) >> 16);
}

__device__ __forceinline__ void load_lds16(const unsigned short* g, unsigned short* l) {
    __builtin_amdgcn_global_load_lds(
        (const __attribute__((address_space(1))) void*)g,
        (__attribute__((address_space(3))) void*)l, 16, 0, 0);
}

// ---------------- zero the f32 logits accumulator (ws is poisoned 0xAA) ----------------
__global__ void zero_logits(float* __restrict__ p, int n) {
    int i = blockIdx.x * blockDim.x + threadIdx.x;
    if (i < n) p[i] = 0.f;
}

// ------------- split hidden f32 -> (hi, lo) bf16 arrays, same layout -------------
__global__ void split_x(const float4* __restrict__ X,
                        unsigned short* __restrict__ hi,
                        unsigned short* __restrict__ lo) {
    int i = blockIdx.x * blockDim.x + threadIdx.x;   // over float4 chunks
    float4 x = X[i];
    ushort4 h, l;
    h.x = f2bf_rne(x.x); l.x = f2bf_rne(x.x - b2f(h.x));
    h.y = f2bf_rne(x.y); l.y = f2bf_rne(x.y - b2f(h.y));
    h.z = f2bf_rne(x.z); l.z = f2bf_rne(x.z - b2f(h.z));
    h.w = f2bf_rne(x.w); l.w = f2bf_rne(x.w - b2f(h.w));
    ((ushort4*)hi)[i] = h;
    ((ushort4*)lo)[i] = l;
}

// ------- transpose W f32 [D][H] -> WT (hi,lo) bf16 [H][D], both matrices (z=0/1) -------
__global__ void split_w(const float* __restrict__ w0, const float* __restrict__ w1,
                        unsigned short* __restrict__ hi, unsigned short* __restrict__ lo) {
    __shared__ float tile[64][65];                   // +1 pad: no bank conflicts
    const float* src = blockIdx.z ? w1 : w0;
    const size_t moff = (size_t)blockIdx.z * H_DIM * D_IN;
    const int t  = threadIdx.x;                      // 256 threads
    const int c4 = (t & 15) * 4;
    const int r0 = (t >> 4) * 4;
    const int bx = blockIdx.x * 64;                  // H direction
    const int by = blockIdx.y * 64;                  // D direction
#pragma unroll
    for (int rr = 0; rr < 4; ++rr) {
        int r = r0 + rr;
        float4 v = *(const float4*)(src + (size_t)(by + r) * H_DIM + bx + c4);
        tile[r][c4 + 0] = v.x; tile[r][c4 + 1] = v.y;
        tile[r][c4 + 2] = v.z; tile[r][c4 + 3] = v.w;
    }
    __syncthreads();
#pragma unroll
    for (int rr = 0; rr < 4; ++rr) {
        int c = r0 + rr;                             // H index within tile
        ushort4 h, l;
        float f0 = tile[c4 + 0][c], f1 = tile[c4 + 1][c];
        float f2 = tile[c4 + 2][c], f3 = tile[c4 + 3][c];
        h.x = f2bf_rne(f0); l.x = f2bf_rne(f0 - b2f(h.x));
        h.y = f2bf_rne(f1); l.y = f2bf_rne(f1 - b2f(h.y));
        h.z = f2bf_rne(f2); l.z = f2bf_rne(f2 - b2f(h.z));
        h.w = f2bf_rne(f3); l.w = f2bf_rne(f3 - b2f(h.w));
        size_t o = moff + (size_t)(bx + c) * D_IN + by + c4;
        *(ushort4*)(hi + o) = h;
        *(ushort4*)(lo + o) = l;
    }
}

// ------------- fused split-f32 GEMM + relu + (.)@W2 reduction -------------
// 3 K-phases: Xhi.WThi + Xhi.WTlo + Xlo.WThi ~= f32 X.W (residual ~2^-18 rel)
// logits[m] += sum_n relu(C[m][n] + b1[n]) * w2[n]   (b1, w2 exact f32)
// 128x128 tile, BK=64, 4 waves, 4x4 frags of 16x16x32 bf16 MFMA.
// LDS layout XOR-swizzled: row r stores global 16B-chunk c at slot c^(r&7)
// -> fragment reads hit each 4-bank group with exactly 2 lanes (conflict-free, m136).
__global__ void __launch_bounds__(256)
gemm_fused3(const unsigned short* __restrict__ Xhi, const unsigned short* __restrict__ Xlo,
            const unsigned short* __restrict__ WThi, const unsigned short* __restrict__ WTlo,
            const float* __restrict__ b1b, const float* __restrict__ b1r,
            const float* __restrict__ w2b, const float* __restrict__ w2r,
            float* __restrict__ logits)              // [2][B][T] f32, atomically accumulated
{
    __shared__ __align__(16) unsigned short Alds[128 * 64];
    __shared__ __align__(16) unsigned short Blds[128 * 64];

    const int t    = threadIdx.x;
    const int wave = t >> 6;
    const int lane = t & 63;
    const int quad = lane >> 4;
    const int lr   = lane & 15;
    const int w_m  = (wave & 1) * 64;
    const int w_n  = (wave >> 1) * 64;

    const int mat = blockIdx.z;
    const int n0  = blockIdx.x * 128;
    const int m0  = blockIdx.y * 128;

    const size_t aoff = (size_t)m0 * D_IN;
    const size_t boff = (size_t)mat * H_DIM * D_IN + (size_t)n0 * D_IN;
    const unsigned short* Aph[3] = { Xhi + aoff, Xhi + aoff, Xlo + aoff };
    const unsigned short* Bph[3] = { WThi + boff, WTlo + boff, WThi + boff };
    const float* b1 = mat ? b1r : b1b;
    const float* w2 = mat ? w2r : w2b;
    float* out = logits + mat * M_ROWS;

    // staging: lane (t) fills LDS slot row srow, physical chunk (t&7).
    // XOR swizzle: that slot must hold global chunk (t&7)^(srow&7).
    const int srow = t >> 3;                         // row within 32-row group
    const int scol = (((t & 7) ^ (srow & 7)) * 8);   // swizzled global chunk -> elems

    f32x4 acc[4][4] = {};

#pragma unroll 1
    for (int ph = 0; ph < 3; ++ph) {
        const unsigned short* A = Aph[ph];
        const unsigned short* B = Bph[ph];
#pragma unroll 1
        for (int kt = 0; kt < D_IN / 64; ++kt) {
            const int k0 = kt * 64;
#pragma unroll
            for (int i = 0; i < 4; ++i) {
                load_lds16(A + (size_t)(i * 32 + srow) * D_IN + k0 + scol, Alds + i * 2048 + wave * 512);
                load_lds16(B + (size_t)(i * 32 + srow) * D_IN + k0 + scol, Blds + i * 2048 + wave * 512);
            }
            __syncthreads();
#pragma unroll
            for (int kc = 0; kc < 2; ++kc) {
                bf16x8 af[4], bfv[4];
                const int pc = ((kc * 4 + quad) ^ (lr & 7)) * 8;   // swizzled physical chunk
#pragma unroll
                for (int i = 0; i < 4; ++i)
                    af[i] = *(const bf16x8*)(Alds + (w_m + i * 16 + lr) * 64 + pc);
#pragma unroll
                for (int j = 0; j < 4; ++j)
                    bfv[j] = *(const bf16x8*)(Blds + (w_n + j * 16 + lr) * 64 + pc);
#pragma unroll
                for (int i = 0; i < 4; ++i)
#pragma unroll
                    for (int j = 0; j < 4; ++j)
                        acc[i][j] = __builtin_amdgcn_mfma_f32_16x16x32_bf16(af[i], bfv[j], acc[i][j], 0, 0, 0);
            }
            __syncthreads();
        }
    }

    // epilogue: relu(C + b1)*w2, reduce over this tile's n, accumulate to logits
    float b1v[4], w2v[4];
#pragma unroll
    for (int j = 0; j < 4; ++j) {
        int n = n0 + w_n + j * 16 + lr;              // C/D col = lane&15
        b1v[j] = b1[n];
        w2v[j] = w2[n];
    }
#pragma unroll
    for (int i = 0; i < 4; ++i) {
#pragma unroll
        for (int r = 0; r < 4; ++r) {
            float s = 0.f;
#pragma unroll
            for (int j = 0; j < 4; ++j) {
                float h = acc[i][j][r] + b1v[j];
                s += fmaxf(h, 0.f) * w2v[j];
            }
            s += __shfl_xor(s, 1, 64);
            s += __shfl_xor(s, 2, 64);
            s += __shfl_xor(s, 4, 64);
            s += __shfl_xor(s, 8, 64);
            if (lr == 0) {
                int m = m0 + w_m + i * 16 + quad * 4 + r;   // C/D row = quad*4 + reg
                atomicAdd(&out[(m & (BATCH - 1)) * T_STEPS + (m >> 2)], s);  // -> [b][t]
            }
        }
    }
}

// ----------------- soft output (f32): out[b*T+t] = logits_b[b][t] + bb2 -----------------
__global__ void soft_out_k(const float* __restrict__ lb,
                           const float* __restrict__ bb2,
                           float* __restrict__ out) {
    int i = blockIdx.x * blockDim.x + threadIdx.x;
    if (i < M_ROWS) out[i] = lb[i] + bb2[0];
}

// --------------------------- serial LIF scan, 4 lanes (f32 out) ---------------------------
__global__ void lif_scan_k(const float* __restrict__ lb,
                           const float* __restrict__ lrr,
                           const float* __restrict__ bb2p,
                           const float* __restrict__ br2p,
                           float* __restrict__ out) {
    int b = threadIdx.x;
    if (b >= BATCH) return;
    const float bb2 = bb2p[0];
    const float br2 = br2p[0];
    const float* xb = lb  + b * T_STEPS;
    const float* xr = lrr + b * T_STEPS;
    float* hb = out + M_ROWS + b * T_STEPS;
    float v = 0.f;
    for (int t0 = 0; t0 < T_STEPS; t0 += 4) {
        float4 xv = *(const float4*)(xb + t0);
        float4 rv = *(const float4*)(xr + t0);
#pragma unroll
        for (int u = 0; u < 4; ++u) {
            float x  = (u == 0 ? xv.x : u == 1 ? xv.y : u == 2 ? xv.z : xv.w) + bb2;
            float rl = (u == 0 ? rv.x : u == 1 ? rv.y : u == 2 ? rv.z : rv.w) + br2;
            v = v + (x - v) * 0.5f;                  // v += (x - v)/TAU, TAU=2 (exact)
            bool spike = (v >= 1.0f);                // heaviside(v - V_TH)
            hb[t0 + u] = spike ? 1.0f : 0.0f;
            v = (spike || (rl > 0.f)) ? 0.f : v;     // hard reset on spike or forced mask
        }
    }
}

extern "C" void kernel_launch(void* const* d_in, const int* in_sizes, int n_in,
                              void* d_out, int out_size, void* d_ws, size_t ws_size,
                              hipStream_t stream) {
    // dict order (confirmed): hidden, Wb1, bb1, Wb2, bb2, Wr1, br1, Wr2, br2
    const float* hidden = (const float*)d_in[0];   // [T,B,D] f32
    const float* Wb1    = (const float*)d_in[1];   // [D,H]
    const float* bb1    = (const float*)d_in[2];   // [H]
    const float* Wb2    = (const float*)d_in[3];   // [H,1]
    const float* bb2    = (const float*)d_in[4];   // [1]
    const float* Wr1    = (const float*)d_in[5];
    const float* br1    = (const float*)d_in[6];
    const float* Wr2    = (const float*)d_in[7];
    const float* br2    = (const float*)d_in[8];
    float* out = (float*)d_out;                    // f32: [soft B*T][hard B*T]

    // ws layout (96.13 MB): Xhi 32MB | Xlo 32MB | WThi 16MB | WTlo 16MB | logits 128KB
    unsigned short* Xhi  = (unsigned short*)d_ws;
    unsigned short* Xlo  = Xhi  + (size_t)M_ROWS * D_IN;
    unsigned short* WThi = Xlo  + (size_t)M_ROWS * D_IN;
    unsigned short* WTlo = WThi + (size_t)2 * H_DIM * D_IN;
    float* logits = (float*)(WTlo + (size_t)2 * H_DIM * D_IN);

    zero_logits<<<dim3((2 * M_ROWS + 255) / 256), 256, 0, stream>>>(logits, 2 * M_ROWS);
    split_x<<<dim3(M_ROWS * D_IN / 4 / 256), 256, 0, stream>>>((const float4*)hidden, Xhi, Xlo);
    split_w<<<dim3(H_DIM / 64, D_IN / 64, 2), 256, 0, stream>>>(Wb1, Wr1, WThi, WTlo);
    gemm_fused3<<<dim3(H_DIM / 128, M_ROWS / 128, 2), 256, 0, stream>>>(
        Xhi, Xlo, WThi, WTlo, bb1, br1, Wb2, Wr2, logits);
    soft_out_k<<<dim3(M_ROWS / 256), 256, 0, stream>>>(logits, bb2, out);
    lif_scan_k<<<1, 64, 0, stream>>>(logits, logits + M_ROWS, bb2, br2, out);
}